// Round 1
// 372.278 us; speedup vs baseline: 1.0645x; 1.0645x over previous
//
#include <hip/hip_runtime.h>
#include <cstdint>
#include <cstddef>

// Problem constants (fixed by reference)
#define B_    4
#define S_    4096
#define DIN_  2048
#define DOUT_ 2048
#define R_    16
#define E_    12
// MULTIPLIER * SCALE == 1.0 — folded away.
// Decomposition: out = x @ W_org^T + (x @ W_down^T) @ combined[b]^T
// Single fused GEMM over M = B*S = 16384 (batch folded into rows; W_org shared).
// Round 4: 256x256 8-phase schedule (T2+T3+T4+T5 per learn_hip m201):
//   - BK=64, 512 threads = 8 waves (2M x 4N), per-wave C = 128x64
//   - 128 KiB LDS, 2 K-tile double buffer, raw s_barrier (no vmcnt(0) drain
//     from __syncthreads), staging via global_load_lds dwordx4
//   - 16x16x32 MFMA: frag lane groups are 16 rows -> slot^(row&7) swizzle is
//     2-way (free) on ds_read_b128
//   - counted-equivalent vmcnt waits only at phases 4 and 8
//   - s_setprio(1) around each 16-MFMA cluster
//   - LoRA rank-16 epilogue: 16x16x32 with zero-padded upper K-half

typedef __bf16 bf16x8  __attribute__((ext_vector_type(8)));
typedef float  floatx4  __attribute__((ext_vector_type(4)));

__device__ __forceinline__ unsigned int f2bf(float f) {
  unsigned int u = __builtin_bit_cast(unsigned int, f);
  u += 0x7fffu + ((u >> 16) & 1u);   // round-to-nearest-even
  return u >> 16;
}

__device__ __forceinline__ void async_copy16(const void* g, void* l) {
  __builtin_amdgcn_global_load_lds(
      (const __attribute__((address_space(1))) void*)g,
      (__attribute__((address_space(3))) void*)l,
      16, 0, 0);
}

// ---------------------------------------------------------------------------
// Kernel 1: x fp32 -> bf16, 8 elems/thread (16B stores).
// ---------------------------------------------------------------------------
__global__ __launch_bounds__(256) void cvt_x_kernel(const float* __restrict__ x,
                                                    unsigned short* __restrict__ xb) {
  size_t idx = ((size_t)blockIdx.x * 256 + threadIdx.x) * 8;
  float4 a = *(const float4*)(x + idx);
  float4 b = *(const float4*)(x + idx + 4);
  uint4 o;
  o.x = f2bf(a.x) | (f2bf(a.y) << 16);
  o.y = f2bf(a.z) | (f2bf(a.w) << 16);
  o.z = f2bf(b.x) | (f2bf(b.y) << 16);
  o.w = f2bf(b.z) | (f2bf(b.w) << 16);
  *(uint4*)(xb + idx) = o;
}

// ---------------------------------------------------------------------------
// Kernel 2 (fused prep): blocks [0,2048): W_org cvt; [2048,2064): W_down cvt;
// [2064,2576): combined[b,o,r] = sum_e gate[b,e]*W_up[e,o,r]. Block-uniform
// branching only.
// ---------------------------------------------------------------------------
__global__ __launch_bounds__(256) void prep_misc_kernel(const float* __restrict__ W_org,
                                                        const float* __restrict__ W_down,
                                                        const float* __restrict__ gate,
                                                        const float* __restrict__ W_up,
                                                        unsigned short* __restrict__ worg,
                                                        unsigned short* __restrict__ wdb,
                                                        unsigned short* __restrict__ cmb) {
  const int bid = blockIdx.x;
  const int tid = threadIdx.x;
  if (bid < 2064) {
    const float* src;
    unsigned short* dst;
    size_t idx;
    if (bid < 2048) { src = W_org;  dst = worg; idx = ((size_t)bid * 256 + tid) * 8; }
    else            { src = W_down; dst = wdb;  idx = ((size_t)(bid - 2048) * 256 + tid) * 8; }
    float4 a = *(const float4*)(src + idx);
    float4 b = *(const float4*)(src + idx + 4);
    uint4 o;
    o.x = f2bf(a.x) | (f2bf(a.y) << 16);
    o.y = f2bf(a.z) | (f2bf(a.w) << 16);
    o.z = f2bf(b.x) | (f2bf(b.y) << 16);
    o.w = f2bf(b.z) | (f2bf(b.w) << 16);
    *(uint4*)(dst + idx) = o;
  } else {
    const int idx = (bid - 2064) * 256 + tid;    // over B*DOUT*R = 131072
    const int b   = idx >> 15;                   // DOUT*R = 32768
    const int orr = idx & 32767;
    float s = 0.f;
#pragma unroll
    for (int e = 0; e < E_; ++e)
      s += gate[b * E_ + e] * W_up[(size_t)e * DOUT_ * R_ + orr];
    cmb[idx] = (unsigned short)f2bf(s);
  }
}

// ---------------------------------------------------------------------------
// Kernel 3: lx = xb @ W_down^T  -> bf16  [16384 rows x 16]  (proven r2 version)
// ---------------------------------------------------------------------------
__global__ __launch_bounds__(256) void lx_kernel(const unsigned short* __restrict__ xb,
                                                 const unsigned short* __restrict__ wdb,
                                                 unsigned short* __restrict__ lxb) {
  const int tid  = threadIdx.x;
  const int lane = tid & 63;
  const int wave = tid >> 6;
  const int grp  = wave >> 1;        // 16-row group within block (0,1)
  const int kh   = wave & 1;         // K-half (0,1)
  const int q    = lane >> 4;
  const int mrow = lane & 15;
  const int row0 = blockIdx.x * 32 + grp * 16;

  floatx4 acc = {};
  const unsigned short* aptr = xb  + (size_t)(row0 + mrow) * DIN_ + kh * 1024 + q * 8;
  const unsigned short* bptr = wdb + (size_t)mrow * DIN_ + kh * 1024 + q * 8;
#pragma unroll 4
  for (int ks = 0; ks < 32; ++ks) {
    bf16x8 av = *(const bf16x8*)(aptr + ks * 32);
    bf16x8 bv = *(const bf16x8*)(bptr + ks * 32);
    acc = __builtin_amdgcn_mfma_f32_16x16x32_bf16(av, bv, acc, 0, 0, 0);
  }

  __shared__ float red[2][64 * 4];
  if (kh == 1) *(floatx4*)&red[grp][lane * 4] = acc;
  __syncthreads();
  if (kh == 0) {
    floatx4 o = *(const floatx4*)&red[grp][lane * 4];
    acc += o;
    // 16x16 C/D layout: col = lane&15 (= r), row = q*4 + reg
#pragma unroll
    for (int rg = 0; rg < 4; ++rg)
      lxb[(size_t)(row0 + q * 4 + rg) * R_ + mrow] = (unsigned short)f2bf(acc[rg]);
  }
}

// ---------------------------------------------------------------------------
// Kernel 4: fused NT GEMM  C = xb @ worg^T + lx @ cmb[batch]^T
// M = 16384 (batch = by>>4), N = 2048, K = 2048.
// 256x256 tile, BK=64, 8-phase double-buffered schedule (see header comment).
// Fragment maps (16x16x32, verified m89/m91):
//   A/B frag: row = lane&15, k = (lane>>4)*8 + j
//   C/D     : col = lane&15, row = (lane>>4)*4 + reg
// LDS tile [256][64] bf16 with 16B-slot swizzle  phys_slot = s ^ (row&7),
// staged linearly with pre-swizzled GLOBAL source (both-sides rule, m201).
// ---------------------------------------------------------------------------
__global__ __launch_bounds__(512, 2) void gemm256_kernel(const unsigned short* __restrict__ A,
                                                         const unsigned short* __restrict__ Bw,
                                                         const unsigned short* __restrict__ lx,
                                                         const unsigned short* __restrict__ cmb,
                                                         float* __restrict__ C) {
  constexpr int K = DIN_;
  __shared__ __align__(16) unsigned short lds[4 * 16384];   // 128 KiB
  unsigned short* ldsA0 = lds;                               // buf0 A  (32 KiB)
  unsigned short* ldsB0 = lds + 16384;                       // buf0 B
  unsigned short* ldsA1 = lds + 32768;                       // buf1 A
  unsigned short* ldsB1 = lds + 49152;                       // buf1 B

  const int tid  = threadIdx.x;
  const int lane = tid & 63;
  const int wave = tid >> 6;
  const int wm   = wave >> 2;       // wave row (0..1) -> 128 rows
  const int wn   = wave & 3;        // wave col (0..3) -> 64 cols
  const int u    = lane & 15;       // frag row
  const int q    = lane >> 4;       // frag k-group / C row-group

  // XCD-aware bijective swizzle (nwg=512, 512%8==0): XCD x owns an 8x8 square.
  const int lin = blockIdx.x;
  const int swz = (lin & 7) * 64 + (lin >> 3);
  const int by  = swz >> 3;         // m-tile 0..63
  const int bx  = swz & 7;          // n-tile 0..7
  const int mBase = by * 256;
  const int nBase = bx * 256;
  const int batch = by >> 4;        // 16 m-tiles per batch; never straddles

  // LDS read bases: row*64 ushorts; swizzle term loop-invariant per lane
  // (row bases are multiples of 16 so row&7 == u&7).
  const int aBase = (wm * 128 + u) * 64;
  const int bBase = (wn * 64 + u) * 64;
  const int swzK0 = (q ^ (u & 7)) << 3;          // kc=0: slot q
  const int swzK1 = ((4 + q) ^ (u & 7)) << 3;    // kc=1: slot 4+q

  floatx4 acc[8][4] = {};
  bf16x8 af[4], bfv[4];

  // Stage one full 256x64 tile (32 KiB): 4 x global_load_lds dwordx4 per
  // thread; LDS dst linear (wave-uniform base + lane*16), global source
  // pre-swizzled so that phys slot sp holds logical slot sp^(row&7).
  auto stage = [&](const unsigned short* __restrict__ src, unsigned short* dstBase,
                   int rowBase, int k0) {
#pragma unroll
    for (int j = 0; j < 4; ++j) {
      const int p   = j * 8192 + tid * 16;     // byte offset in 32 KiB region
      const int row = p >> 7;                  // 128 B per row
      const int sp  = (p >> 4) & 7;            // phys 16B slot
      const int ss  = sp ^ (row & 7);          // source slot
      async_copy16(src + (size_t)(rowBase + row) * K + k0 + ss * 8,
                   (char*)dstBase + p);
    }
  };

  // ---- prologue: tile 0 -> buf0, full drain once ----
  stage(A,  ldsA0, mBase, 0);
  stage(Bw, ldsB0, nBase, 0);
  asm volatile("s_waitcnt vmcnt(0)" ::: "memory");
  __builtin_amdgcn_s_barrier();

  // One phase: {ds-read frags | stage issue} -> barrier -> lgkmcnt(0) ->
  // setprio(1) 16 MFMA setprio(0) -> [vm wait] -> barrier.
  // B-frags are reused across the h=0/h=1 pair (24 ds_read_b128 per K-tile).
#define PHASE(h, SWZ, bufA, bufB, READB, STAGECODE, VMWAIT)                      \
  {                                                                              \
    _Pragma("unroll")                                                            \
    for (int mf2 = 0; mf2 < 4; ++mf2)                                            \
      af[mf2] = *(const bf16x8*)&bufA[aBase + ((h) * 4 + mf2) * 1024 + (SWZ)];   \
    if (READB) {                                                                 \
      _Pragma("unroll")                                                          \
      for (int nf = 0; nf < 4; ++nf)                                             \
        bfv[nf] = *(const bf16x8*)&bufB[bBase + nf * 1024 + (SWZ)];              \
    }                                                                            \
    STAGECODE;                                                                   \
    __builtin_amdgcn_s_barrier();                                                \
    asm volatile("s_waitcnt lgkmcnt(0)" ::: "memory");                           \
    __builtin_amdgcn_s_setprio(1);                                               \
    _Pragma("unroll")                                                            \
    for (int mf2 = 0; mf2 < 4; ++mf2) {                                          \
      _Pragma("unroll")                                                          \
      for (int nf = 0; nf < 4; ++nf)                                             \
        acc[(h) * 4 + mf2][nf] = __builtin_amdgcn_mfma_f32_16x16x32_bf16(        \
            af[mf2], bfv[nf], acc[(h) * 4 + mf2][nf], 0, 0, 0);                  \
    }                                                                            \
    __builtin_amdgcn_s_setprio(0);                                               \
    VMWAIT;                                                                      \
    __builtin_amdgcn_s_barrier();                                                \
  }

  // Main loop: iteration computes K-tiles 2it (buf0, phases 1-4) and 2it+1
  // (buf1, phases 5-8). Stage schedule (region provably dead at issue):
  //   p1: A(2it+1)->buf1   p2: B(2it+1)->buf1   (buf1 dead since prev p8)
  //   p5: A(2it+2)->buf0   p6: B(2it+2)->buf0   (buf0 dead after p4)
  // At p4/p8 waits nothing NEWER than the required tile is in flight, so
  // vmcnt(0) == the counted wait; prefetch distance 2-3 phases.
  for (int it = 0; it < 16; ++it) {
    const int kB = it * 128 + 64;    // odd tile k0
    const int kN = it * 128 + 128;   // next even tile k0
    const bool more = (it < 15);
    PHASE(0, swzK0, ldsA0, ldsB0, true,  stage(A,  ldsA1, mBase, kB), )
    PHASE(1, swzK0, ldsA0, ldsB0, false, stage(Bw, ldsB1, nBase, kB), )
    PHASE(0, swzK1, ldsA0, ldsB0, true,  , )
    PHASE(1, swzK1, ldsA0, ldsB0, false, ,
          asm volatile("s_waitcnt vmcnt(0)" ::: "memory"))
    PHASE(0, swzK0, ldsA1, ldsB1, true,  if (more) stage(A,  ldsA0, mBase, kN), )
    PHASE(1, swzK0, ldsA1, ldsB1, false, if (more) stage(Bw, ldsB0, nBase, kN), )
    PHASE(0, swzK1, ldsA1, ldsB1, true,  , )
    PHASE(1, swzK1, ldsA1, ldsB1, false, ,
          asm volatile("s_waitcnt vmcnt(0)" ::: "memory"))
  }
#undef PHASE

  // ---- rank-16 LoRA epilogue: 16x16x32 with zero upper K-half (q>=2) ----
  {
    bf16x8 z = {};
    bf16x8 la[8], lb[4];
#pragma unroll
    for (int mf = 0; mf < 8; ++mf) {
      const size_t row = (size_t)(mBase + wm * 128 + mf * 16 + u);
      const unsigned short* p = lx + row * R_ + (q & 1) * 8;   // clamped addr
      la[mf] = (q < 2) ? *(const bf16x8*)p : z;
    }
#pragma unroll
    for (int nf = 0; nf < 4; ++nf) {
      const size_t brow = (size_t)batch * DOUT_ + nBase + wn * 64 + nf * 16 + u;
      const unsigned short* p = cmb + brow * R_ + (q & 1) * 8;
      lb[nf] = (q < 2) ? *(const bf16x8*)p : z;
    }
#pragma unroll
    for (int mf = 0; mf < 8; ++mf)
#pragma unroll
      for (int nf = 0; nf < 4; ++nf)
        acc[mf][nf] = __builtin_amdgcn_mfma_f32_16x16x32_bf16(la[mf], lb[nf],
                                                              acc[mf][nf], 0, 0, 0);
  }

  // ---- store: col = nBase + wn*64 + nf*16 + u; row = ... + q*4 + rg ----
#pragma unroll
  for (int mf = 0; mf < 8; ++mf) {
    const int grow0 = mBase + wm * 128 + mf * 16 + q * 4;
#pragma unroll
    for (int nf = 0; nf < 4; ++nf) {
      const int gcol = nBase + wn * 64 + nf * 16 + u;
#pragma unroll
      for (int rg = 0; rg < 4; ++rg)
        C[(size_t)(grow0 + rg) * DOUT_ + gcol] = acc[mf][nf][rg];
    }
  }
}

// ---------------------------------------------------------------------------
extern "C" void kernel_launch(void* const* d_in, const int* in_sizes, int n_in,
                              void* d_out, int out_size, void* d_ws, size_t ws_size,
                              hipStream_t stream) {
  const float* x      = (const float*)d_in[0];
  const float* gate   = (const float*)d_in[1];
  const float* W_org  = (const float*)d_in[2];
  const float* W_down = (const float*)d_in[3];
  const float* W_up   = (const float*)d_in[4];
  float* out = (float*)d_out;

  // workspace layout (ushort elems):
  unsigned short* xb   = (unsigned short*)d_ws;             // 33,554,432
  unsigned short* worg = xb   + (size_t)B_ * S_ * DIN_;     //  4,194,304
  unsigned short* wdb  = worg + (size_t)DOUT_ * DIN_;       //     32,768
  unsigned short* lxb  = wdb  + (size_t)R_ * DIN_;          //    262,144
  unsigned short* cmb  = lxb  + (size_t)B_ * S_ * R_;       //    131,072

  // 1) x -> bf16
  cvt_x_kernel<<<(B_ * S_ * DIN_) / 2048, 256, 0, stream>>>(x, xb);

  // 2) fused prep: W_org cvt + W_down cvt + combined
  prep_misc_kernel<<<2576, 256, 0, stream>>>(W_org, W_down, gate, W_up, worg, wdb, cmb);

  // 3) lx = xb @ W_down^T  (bf16)
  lx_kernel<<<(B_ * S_) / 32, 256, 0, stream>>>(xb, wdb, lxb);

  // 4) out = xb @ worg^T + lx @ cmb[batch]^T  (fp32 out), 256^2 8-phase
  gemm256_kernel<<<512, 512, 0, stream>>>(xb, worg, lxb, cmb, out);
}